// Round 7
// baseline (282.312 us; speedup 1.0000x reference)
//
#include <hip/hip_runtime.h>

#define DEV __device__ __forceinline__

constexpr int A_ = 64, DE = 128, M_ = 512, DH = 64;
constexpr int REC  = 208;  // global record: [0]=max [1]=sum [16..144)=e128 [144..208)=v64 ; 832 B, 64B-aligned
constexpr int RECL = 196;  // LDS record:    [0]=max [1]=sum [4..132)=e128 [132..196)=v64

typedef float vf4 __attribute__((ext_vector_type(4)));
typedef float vf2 __attribute__((ext_vector_type(2)));

DEV vf4 nt4(const float* p) { return __builtin_nontemporal_load((const vf4*)p); }

DEV float wred_sum64(float v) {
#pragma unroll
    for (int o = 1; o < 64; o <<= 1) v += __shfl_xor(v, o, 64);
    return v;
}

// ---------------- Kernel 1: per-(b,m) hyperbolic dH2 + log_map ----------------
__global__ __launch_bounds__(256) void k_hyp(const float* __restrict__ curr_hyp,
                                             const float* __restrict__ demo_hyp,
                                             float* __restrict__ dH2,
                                             float* __restrict__ logv) {
    const int lane = threadIdx.x & 63;
    const int r    = (blockIdx.x << 2) + (threadIdx.x >> 6);  // [0, B*M)
    const int b    = r >> 9;                                  // M=512

    float x = curr_hyp[(b << 6) + lane];
    float y = demo_hyp[((size_t)r << 6) + lane];
    const float mx = 1.0f - 1e-5f;

    float x2r = wred_sum64(x * x);
    float xn  = fmaxf(sqrtf(x2r), 1e-15f);
    float sx  = xn > mx ? mx / xn : 1.0f;
    x *= sx;
    float x2 = x2r * sx * sx;
    float y2r = wred_sum64(y * y);
    float yn  = fmaxf(sqrtf(y2r), 1e-15f);
    float sy  = yn > mx ? mx / yn : 1.0f;
    y *= sy;
    float y2 = y2r * sy * sy;

    float xy = wred_sum64(x * y);
    float num = (1.f - 2.f * xy + y2) * (-x) + (1.f - x2) * y;
    float den = fmaxf(1.f - 2.f * xy + x2 * y2, 1e-15f);
    float u   = num / den;

    float u2  = wred_sum64(u * u);
    float un  = fmaxf(sqrtf(u2), 1e-15f);
    float arg = fminf(un, 1.f - 1e-7f);
    float at  = 0.5f * __logf((1.f + arg) / (1.f - arg));  // atanh

    if (lane == 0) dH2[r] = 4.f * at * at;

    float lamden = fmaxf(1.f - x2, 1e-15f);  // 2/lambda
    float ls     = lamden * at / un;
    logv[((size_t)r << 6) + lane] = ls * u;
}

// ---------------- Kernel 2: split-K partials, NT streaming ----------------
// grid = b(8) x mc(16) x ag(8) = 1024 blocks, 256 thr = 4 waves.
// Block: m in [mc*32, mc*32+32), a in [ag*8, ag*8+8); 4KB-contiguous NT row reads.
// Wave w: 8 m's. Lane: h=lane>>5 (a-parity), dc=lane&31 (d-slice 4dc..4dc+4);
// float4 k covers a_local=2k+h. logv/dH2 fragments preloaded to registers (no LDS
// staging -> vmcnt queue stays pure NT stream). Block-merge in LDS; NT record writes.
__global__ __launch_bounds__(256, 5) void k_part(const float* __restrict__ curr_rho,
                                                 const float* __restrict__ demo_rho,
                                                 const float* __restrict__ dH2,
                                                 const float* __restrict__ logv,
                                                 float* __restrict__ part) {
    __shared__ __align__(16) float mb[32 * RECL];  // 24.5 KB merge buffer

    const int t   = threadIdx.x;
    const int blk = blockIdx.x;
    const int b   = blk >> 7, mc = (blk >> 3) & 15, ag = blk & 7;
    const int lane = t & 63, w = t >> 6;
    const int h = lane >> 5, dc = lane & 31;

    // per-row logv fragments + dH2 (registers; issued first -> oldest in queue)
    float2 lvr[8];
    float  dhr[8];
    {
        const float* lsrc = logv + ((size_t)b * M_ + mc * 32 + 8 * w) * DH + dc * 2;
        const float* dsrc = dH2 + b * M_ + mc * 32 + 8 * w;
#pragma unroll
        for (int i = 0; i < 8; i++) lvr[i] = *(const float2*)(lsrc + (size_t)i * DH);
#pragma unroll
        for (int i = 0; i < 8; i++) dhr[i] = dsrc[i];
    }

    // q fragments: qf[k] = curr_rho[b, ag*8 + 2k + h, 4dc .. 4dc+4)
    float qf[4][4];
#pragma unroll
    for (int k = 0; k < 4; k++) {
        int a = ag * 8 + 2 * k + h;
        float4 q = *(const float4*)(curr_rho + ((size_t)b * A_ + a) * DE + dc * 4);
        qf[k][0] = q.x; qf[k][1] = q.y; qf[k][2] = q.z; qf[k][3] = q.w;
    }

    float mAcc[4], sAcc[4], eAcc[4][4], vAcc[4][2];
#pragma unroll
    for (int k = 0; k < 4; k++) {
        mAcc[k] = -1e30f; sAcc[k] = 0.f;
        eAcc[k][0] = eAcc[k][1] = eAcc[k][2] = eAcc[k][3] = 0.f;
        vAcc[k][0] = vAcc[k][1] = 0.f;
    }

    // wave w's rows: local m = 8w + i
    const float* rb = demo_rho + (((size_t)b * M_ + mc * 32 + 8 * w) * A_ + ag * 8) * DE;
    const size_t rstride = (size_t)A_ * DE;  // 8192 floats between m-rows

    vf4 c0[4], c1[4];
#pragma unroll
    for (int k = 0; k < 4; k++) c0[k] = nt4(rb + lane * 4 + k * 256);
#pragma unroll
    for (int k = 0; k < 4; k++) c1[k] = nt4(rb + rstride + lane * 4 + k * 256);

    for (int i = 0; i < 8; ++i) {
        vf4 nx[4];
        if (i < 6) {
            const float* nb = rb + (size_t)(i + 2) * rstride;
#pragma unroll
            for (int k = 0; k < 4; k++) nx[k] = nt4(nb + lane * 4 + k * 256);
        }
        const float2 lvv = lvr[i];
        const float  dh  = dhr[i];

        float ps[4];
#pragma unroll
        for (int k = 0; k < 4; k++) {
            float p = 0.f;
#pragma unroll
            for (int j = 0; j < 4; j++) { float d = qf[k][j] - c0[k][j]; p = fmaf(d, d, p); }
            ps[k] = p;
        }
        // half-wave reduce (lanes share h; xor<32 stays in-half)
#pragma unroll
        for (int o = 1; o < 32; o <<= 1) {
#pragma unroll
            for (int k = 0; k < 4; k++) ps[k] += __shfl_xor(ps[k], o, 64);
        }
#pragma unroll
        for (int k = 0; k < 4; k++) {
            float sc = -(dh + ps[k]);
            float nm = fmaxf(mAcc[k], sc);
            float r  = __expf(mAcc[k] - nm);
            float wt = __expf(sc - nm);
            sAcc[k] = sAcc[k] * r + wt;
            eAcc[k][0] = fmaf(eAcc[k][0], r, wt * c0[k][0]);
            eAcc[k][1] = fmaf(eAcc[k][1], r, wt * c0[k][1]);
            eAcc[k][2] = fmaf(eAcc[k][2], r, wt * c0[k][2]);
            eAcc[k][3] = fmaf(eAcc[k][3], r, wt * c0[k][3]);
            vAcc[k][0] = fmaf(vAcc[k][0], r, wt * lvv.x);
            vAcc[k][1] = fmaf(vAcc[k][1], r, wt * lvv.y);
            mAcc[k] = nm;
        }
#pragma unroll
        for (int k = 0; k < 4; k++) { c0[k] = c1[k]; c1[k] = nx[k]; }
    }

    // dump wave-partials: slot = w*8 + a_local (stride 196 ≡ 4 mod 32 banks)
#pragma unroll
    for (int k = 0; k < 4; k++) {
        int slot = w * 8 + 2 * k + h;
        *(float4*)&mb[slot * RECL + 4 + dc * 4] =
            make_float4(eAcc[k][0], eAcc[k][1], eAcc[k][2], eAcc[k][3]);
        *(float2*)&mb[slot * RECL + 132 + dc * 2] = make_float2(vAcc[k][0], vAcc[k][1]);
        if (dc == 0) { mb[slot * RECL] = mAcc[k]; mb[slot * RECL + 1] = sAcc[k]; }
    }
    __syncthreads();

    // wave w merges a_local in {w, w+4} across the 4 wave-partials; NT record write
    for (int al = w; al < 8; al += 4) {
        float m0 = mb[(0 * 8 + al) * RECL], m1 = mb[(1 * 8 + al) * RECL];
        float m2 = mb[(2 * 8 + al) * RECL], m3 = mb[(3 * 8 + al) * RECL];
        float g = fmaxf(fmaxf(m0, m1), fmaxf(m2, m3));
        float f0 = __expf(m0 - g), f1 = __expf(m1 - g);
        float f2 = __expf(m2 - g), f3 = __expf(m3 - g);
        float gs = mb[al * RECL + 1] * f0 + mb[(8 + al) * RECL + 1] * f1 +
                   mb[(16 + al) * RECL + 1] * f2 + mb[(24 + al) * RECL + 1] * f3;
        float* rec = part + (((size_t)(b * A_ + ag * 8 + al)) * 16 + mc) * REC;
        float e0 = f0 * mb[al * RECL + 4 + 2 * lane] + f1 * mb[(8 + al) * RECL + 4 + 2 * lane] +
                   f2 * mb[(16 + al) * RECL + 4 + 2 * lane] + f3 * mb[(24 + al) * RECL + 4 + 2 * lane];
        float e1 = f0 * mb[al * RECL + 5 + 2 * lane] + f1 * mb[(8 + al) * RECL + 5 + 2 * lane] +
                   f2 * mb[(16 + al) * RECL + 5 + 2 * lane] + f3 * mb[(24 + al) * RECL + 5 + 2 * lane];
        vf2 ev; ev[0] = e0; ev[1] = e1;
        __builtin_nontemporal_store(ev, (vf2*)&rec[16 + 2 * lane]);
        float vv = f0 * mb[al * RECL + 132 + lane] + f1 * mb[(8 + al) * RECL + 132 + lane] +
                   f2 * mb[(16 + al) * RECL + 132 + lane] + f3 * mb[(24 + al) * RECL + 132 + lane];
        __builtin_nontemporal_store(vv, &rec[144 + lane]);
        if (lane == 0) {
            __builtin_nontemporal_store(g,  &rec[0]);
            __builtin_nontemporal_store(gs, &rec[1]);
        }
    }
}

// ---------------- Kernel 3: merge 16 partials + epilogue ----------------
__global__ __launch_bounds__(256) void k_merge(const float* __restrict__ part,
                                               const float* __restrict__ curr_hyp,
                                               const float* __restrict__ We,
                                               const float* __restrict__ Wh,
                                               const float* __restrict__ gamma,
                                               const float* __restrict__ beta,
                                               float* __restrict__ out) {
    __shared__ float eh[192];  // [0:128) e_out, [128:192) h
    __shared__ float vv[64];

    const int t = threadIdx.x, w = t >> 6, lane = t & 63;
    const int blk = blockIdx.x, b = blk >> 6;
    const float* pbase = part + (size_t)blk * 16 * REC;

    float mk[16];
#pragma unroll
    for (int k = 0; k < 16; k++) mk[k] = pbase[k * REC];
    float g = mk[0];
#pragma unroll
    for (int k = 1; k < 16; k++) g = fmaxf(g, mk[k]);
    float fk[16];
    float gs = 0.f;
#pragma unroll
    for (int k = 0; k < 16; k++) { fk[k] = __expf(mk[k] - g); gs += pbase[k * REC + 1] * fk[k]; }
    const float inv = 1.f / gs;

    if (t < 192) {
        const int off = (t < 128) ? (16 + t) : (144 + (t - 128));
        float acc = 0.f;
#pragma unroll
        for (int k = 0; k < 16; k++) acc = fmaf(pbase[k * REC + off], fk[k], acc);
        acc *= inv;
        if (t < 128) eh[t] = acc;
        else vv[t - 128] = acc;
    }
    __syncthreads();

    if (w == 0) {
        float v = vv[lane];
        const float mxb = 1.0f - 1e-5f;
        float x = curr_hyp[(b << 6) + lane];
        float x2r = wred_sum64(x * x);
        float xn  = fmaxf(sqrtf(x2r), 1e-15f);
        float sx  = xn > mxb ? mxb / xn : 1.f;
        x *= sx;
        float x2 = x2r * sx * sx;
        float lamden = fmaxf(1.f - x2, 1e-15f);  // 2/lambda

        float v2 = wred_sum64(v * v);
        float vn = fmaxf(sqrtf(v2), 1e-15f);
        float targ   = vn / lamden;              // lambda*vnorm/2
        float e2     = __expf(2.f * targ);
        float factor = 1.f - 2.f / (e2 + 1.f);   // tanh, inf-safe
        float wvv    = v * (factor / vn);

        float w2 = wred_sum64(wvv * wvv);
        float xw = wred_sum64(x * wvv);
        float num = (1.f + 2.f * xw + w2) * x + (1.f - x2) * wvv;
        float den = fmaxf(1.f + 2.f * xw + x2 * w2, 1e-15f);
        float hq  = num / den;
        float h2  = wred_sum64(hq * hq);
        float hn  = fmaxf(sqrtf(h2), 1e-15f);
        float shh = hn > mxb ? mxb / hn : 1.f;
        hq *= shh;
        eh[128 + lane] = hq;  // same-wave visibility

        float ze = 0.f;
        const float* werow = We + lane * 128;
#pragma unroll
        for (int d0 = 0; d0 < 128; d0 += 4) {
            float4 wv4 = *(const float4*)(werow + d0);
            ze = fmaf(eh[d0 + 0], wv4.x, ze);
            ze = fmaf(eh[d0 + 1], wv4.y, ze);
            ze = fmaf(eh[d0 + 2], wv4.z, ze);
            ze = fmaf(eh[d0 + 3], wv4.w, ze);
        }
        float zh = 0.f;
        const float* whrow = Wh + lane * 64;
#pragma unroll
        for (int d0 = 0; d0 < 64; d0 += 4) {
            float4 wv4 = *(const float4*)(whrow + d0);
            zh = fmaf(eh[128 + d0 + 0], wv4.x, zh);
            zh = fmaf(eh[128 + d0 + 1], wv4.y, zh);
            zh = fmaf(eh[128 + d0 + 2], wv4.z, zh);
            zh = fmaf(eh[128 + d0 + 3], wv4.w, zh);
        }
        float ssum = wred_sum64(ze + zh);
        float mean = ssum * (1.f / 128.f);
        float sq   = wred_sum64(ze * ze + zh * zh);
        float var  = sq * (1.f / 128.f) - mean * mean;
        float rinv = rsqrtf(var + 1e-5f);
        float oe = (ze - mean) * rinv * gamma[lane] + beta[lane];
        float oh = (zh - mean) * rinv * gamma[64 + lane] + beta[64 + lane];
        out[(size_t)blk * 128 + lane]      = oe;
        out[(size_t)blk * 128 + 64 + lane] = oh;
    }
}

extern "C" void kernel_launch(void* const* d_in, const int* in_sizes, int n_in,
                              void* d_out, int out_size, void* d_ws, size_t ws_size,
                              hipStream_t stream) {
    const float* curr_rho = (const float*)d_in[0];
    const float* curr_hyp = (const float*)d_in[1];
    const float* demo_rho = (const float*)d_in[2];
    const float* demo_hyp = (const float*)d_in[3];
    const float* We       = (const float*)d_in[4];
    const float* Wh       = (const float*)d_in[5];
    const float* gamma    = (const float*)d_in[6];
    const float* beta     = (const float*)d_in[7];
    float* out = (float*)d_out;

    float* ws   = (float*)d_ws;
    float* dH2  = ws;                     // 4096 floats
    float* logv = ws + 4096;              // 262144 floats
    float* part = ws + 4096 + 262144;     // 512*16*208 floats = 6.8 MB (64B-aligned)

    k_hyp<<<1024, 256, 0, stream>>>(curr_hyp, demo_hyp, dH2, logv);
    k_part<<<1024, 256, 0, stream>>>(curr_rho, demo_rho, dH2, logv, part);
    k_merge<<<512, 256, 0, stream>>>(part, curr_hyp, We, Wh, gamma, beta, out);
}